// Round 3
// baseline (1579.807 us; speedup 1.0000x reference)
//
#include <hip/hip_runtime.h>
#include <math.h>

// Extract component kk (compile-time after unroll) from a float4.
#define C4(v,k) ((k)==0 ? (v).x : (k)==1 ? (v).y : (k)==2 ? (v).z : (v).w)

__device__ __forceinline__ float sigm(float v) { return 1.0f / (1.0f + __expf(-v)); }

constexpr int NROWS = 200000;
constexpr int TM    = 16;            // rows per block tile
constexpr int TILES = NROWS / TM;    // 12500, exact
constexpr int XDIM  = 480;

// One fused kernel; block role by blockIdx:
//   [0, TILES)        -> l=0 path (cols 0..127,  hidden 256)
//   [TILES, 2*TILES)  -> l=1 path (cols 128..319, 64 ch x 3, hidden 128x3)
//   [2*TILES, 3*TILES)-> l=2 path (cols 320..479, 32 ch x 5, hidden 64x5)
extern "C" __global__ void __launch_bounds__(256)
ff_fused(const float* __restrict__ x,
         const float* __restrict__ nw0, const float* __restrict__ nb0,
         const float* __restrict__ nw1, const float* __restrict__ nw2,
         const float* __restrict__ pw0, const float* __restrict__ pw1,
         const float* __restrict__ pw2,
         const float* __restrict__ qw0, const float* __restrict__ qw1,
         const float* __restrict__ qw2,
         float* __restrict__ out)
{
    __shared__ float lds[12288];     // 48 KB, carved per path
    const int tid = threadIdx.x;
    const int bid = blockIdx.x;

    if (bid < TILES) {
        //===================== l = 0 =====================
        const int row0 = bid * TM;
        float* xr = lds;          // [16][128] raw x (residual)
        float* xn = lds + 2048;   // [16][128] layernormed
        float* hb = lds + 4096;   // [16][256] gated hidden

        { // ---- load + layernorm (16 thr/row, 8 ch/thr) ----
            const int r = tid >> 4, t = tid & 15;
            const float* xp = x + (size_t)(row0 + r) * XDIM + t * 8;
            float4 a = *(const float4*)xp;
            float4 b = *(const float4*)(xp + 4);
            *(float4*)(xr + r * 128 + t * 8)     = a;
            *(float4*)(xr + r * 128 + t * 8 + 4) = b;
            float s  = a.x + a.y + a.z + a.w + b.x + b.y + b.z + b.w;
            float ss = a.x*a.x + a.y*a.y + a.z*a.z + a.w*a.w
                     + b.x*b.x + b.y*b.y + b.z*b.z + b.w*b.w;
            #pragma unroll
            for (int m = 8; m >= 1; m >>= 1) { s += __shfl_xor(s, m); ss += __shfl_xor(ss, m); }
            const float mu  = s * (1.0f/128.0f);
            const float var = ss * (1.0f/128.0f) - mu * mu;
            const float ri  = 1.0f / sqrtf(var + 1e-5f);
            float4 wa = *(const float4*)(nw0 + t*8);
            float4 wb = *(const float4*)(nw0 + t*8 + 4);
            float4 ba = *(const float4*)(nb0 + t*8);
            float4 bb = *(const float4*)(nb0 + t*8 + 4);
            float4 ya, yb;
            ya.x = (a.x-mu)*ri*wa.x + ba.x;  ya.y = (a.y-mu)*ri*wa.y + ba.y;
            ya.z = (a.z-mu)*ri*wa.z + ba.z;  ya.w = (a.w-mu)*ri*wa.w + ba.w;
            yb.x = (b.x-mu)*ri*wb.x + bb.x;  yb.y = (b.y-mu)*ri*wb.y + bb.y;
            yb.z = (b.z-mu)*ri*wb.z + bb.z;  yb.w = (b.w-mu)*ri*wb.w + bb.w;
            *(float4*)(xn + r*128 + t*8)     = ya;
            *(float4*)(xn + r*128 + t*8 + 4) = yb;
        }
        __syncthreads();

        { // ---- pre-linear [128->256] + sigmoid; 4 rows x 4 cols per thread ----
            const int cg = tid & 63;          // col base, cols cg+64j
            const int rg = tid >> 6;          // rows 4rg..4rg+3
            float acc[4][4] = {};
            const float* wp = pw0 + cg;
            const float* xp = xn + rg * 4 * 128;
            for (int k = 0; k < 128; k += 4) {
                float4 x0 = *(const float4*)(xp + k);
                float4 x1 = *(const float4*)(xp + 128 + k);
                float4 x2 = *(const float4*)(xp + 256 + k);
                float4 x3 = *(const float4*)(xp + 384 + k);
                #pragma unroll
                for (int kk = 0; kk < 4; ++kk) {
                    const float w[4]  = { wp[0], wp[64], wp[128], wp[192] };
                    wp += 256;
                    const float xv[4] = { C4(x0,kk), C4(x1,kk), C4(x2,kk), C4(x3,kk) };
                    #pragma unroll
                    for (int i = 0; i < 4; ++i)
                        #pragma unroll
                        for (int j = 0; j < 4; ++j)
                            acc[i][j] = fmaf(xv[i], w[j], acc[i][j]);
                }
            }
            const float sc = 0.08838834764831845f;   // 1/sqrt(128)
            #pragma unroll
            for (int i = 0; i < 4; ++i) {
                float* hp = hb + (rg*4 + i) * 256 + cg;
                #pragma unroll
                for (int j = 0; j < 4; ++j)
                    hp[64*j] = sigm(acc[i][j] * sc);
            }
        }
        __syncthreads();

        { // ---- post-linear [256->128] + residual; 4 rows x 2 cols ----
            const int cg = tid & 63;
            const int rg = tid >> 6;
            float acc[4][2] = {};
            const float* wp = qw0 + cg;
            const float* hp = hb + rg * 4 * 256;
            for (int k = 0; k < 256; k += 4) {
                float4 h0 = *(const float4*)(hp + k);
                float4 h1 = *(const float4*)(hp + 256 + k);
                float4 h2 = *(const float4*)(hp + 512 + k);
                float4 h3 = *(const float4*)(hp + 768 + k);
                #pragma unroll
                for (int kk = 0; kk < 4; ++kk) {
                    const float w[2]  = { wp[0], wp[64] };
                    wp += 128;
                    const float hv[4] = { C4(h0,kk), C4(h1,kk), C4(h2,kk), C4(h3,kk) };
                    #pragma unroll
                    for (int i = 0; i < 4; ++i) {
                        acc[i][0] = fmaf(hv[i], w[0], acc[i][0]);
                        acc[i][1] = fmaf(hv[i], w[1], acc[i][1]);
                    }
                }
            }
            const float sc = 0.0625f;                // 1/sqrt(256)
            #pragma unroll
            for (int i = 0; i < 4; ++i) {
                const int r = rg*4 + i;
                float* op = out + (size_t)(row0 + r) * XDIM;
                op[cg]      = xr[r*128 + cg]      + acc[i][0]*sc;
                op[cg + 64] = xr[r*128 + cg + 64] + acc[i][1]*sc;
            }
        }
    } else if (bid < 2*TILES) {
        //===================== l = 1 (64 ch x 3 comps) =====================
        const int row0 = (bid - TILES) * TM;
        float* xr = lds;           // [16][192] raw, layout c*3+m
        float* xn = lds + 3072;    // [3][16][64]  m-major normalized
        float* hb = lds + 6144;    // [3][16][128] m-major gated hidden

        for (int idx = tid; idx < 768; idx += 256) {
            const int r = idx / 48, c4 = idx - r*48;
            *(float4*)(xr + r*192 + c4*4) =
                *(const float4*)(x + (size_t)(row0 + r)*XDIM + 128 + c4*4);
        }
        __syncthreads();

        { // ---- RMS over channel norms (16 thr/row, 4 ch/thr) ----
            const int r = tid >> 4, t = tid & 15;
            const float* xp = xr + r*192 + t*12;     // channels 4t..4t+3
            float v[12];
            #pragma unroll
            for (int i = 0; i < 12; ++i) v[i] = xp[i];
            float s = 0.f;
            #pragma unroll
            for (int i = 0; i < 12; ++i) s += v[i]*v[i];
            #pragma unroll
            for (int m = 8; m >= 1; m >>= 1) s += __shfl_xor(s, m);
            const float ri = 1.0f / sqrtf(s * (1.0f/64.0f) + 1e-5f);
            float w[4];
            *(float4*)w = *(const float4*)(nw1 + t*4);
            #pragma unroll
            for (int m = 0; m < 3; ++m) {
                float4 y;
                y.x = v[0+m]*ri*w[0];  y.y = v[3+m]*ri*w[1];
                y.z = v[6+m]*ri*w[2];  y.w = v[9+m]*ri*w[3];
                *(float4*)(xn + m*1024 + r*64 + t*4) = y;
            }
        }
        __syncthreads();

        { // ---- pre-linear [64->128] x3 comps + norm-gate; 4r x 3m x 2c ----
            const int cg = tid & 63;
            const int rg = tid >> 6;
            float acc[4][3][2] = {};
            const float* wp = pw1 + cg;
            for (int k = 0; k < 64; k += 4) {
                float4 xv[4][3];
                #pragma unroll
                for (int i = 0; i < 4; ++i)
                    #pragma unroll
                    for (int m = 0; m < 3; ++m)
                        xv[i][m] = *(const float4*)(xn + m*1024 + (rg*4+i)*64 + k);
                #pragma unroll
                for (int kk = 0; kk < 4; ++kk) {
                    const float w[2] = { wp[0], wp[64] };
                    wp += 128;
                    #pragma unroll
                    for (int i = 0; i < 4; ++i)
                        #pragma unroll
                        for (int m = 0; m < 3; ++m) {
                            acc[i][m][0] = fmaf(C4(xv[i][m],kk), w[0], acc[i][m][0]);
                            acc[i][m][1] = fmaf(C4(xv[i][m],kk), w[1], acc[i][m][1]);
                        }
                }
            }
            const float sc = 0.125f;                 // 1/sqrt(64)
            #pragma unroll
            for (int i = 0; i < 4; ++i) {
                const int r = rg*4 + i;
                #pragma unroll
                for (int j = 0; j < 2; ++j) {
                    const int o = cg + 64*j;
                    const float h0 = acc[i][0][j]*sc, h1 = acc[i][1][j]*sc, h2 = acc[i][2][j]*sc;
                    const float g = sigm(sqrtf(h0*h0 + h1*h1 + h2*h2 + 1e-12f));
                    hb[0*2048 + r*128 + o] = h0*g;
                    hb[1*2048 + r*128 + o] = h1*g;
                    hb[2*2048 + r*128 + o] = h2*g;
                }
            }
        }
        __syncthreads();

        { // ---- post-linear [128->64] x3 + residual; 2r x 3m x 2c ----
            const int cg = tid & 31;
            const int rg = tid >> 5;
            float acc[2][3][2] = {};
            const float* wp = qw1 + cg;
            for (int k = 0; k < 128; k += 4) {
                float4 hv[2][3];
                #pragma unroll
                for (int i = 0; i < 2; ++i)
                    #pragma unroll
                    for (int m = 0; m < 3; ++m)
                        hv[i][m] = *(const float4*)(hb + m*2048 + (rg*2+i)*128 + k);
                #pragma unroll
                for (int kk = 0; kk < 4; ++kk) {
                    const float w[2] = { wp[0], wp[32] };
                    wp += 64;
                    #pragma unroll
                    for (int i = 0; i < 2; ++i)
                        #pragma unroll
                        for (int m = 0; m < 3; ++m) {
                            acc[i][m][0] = fmaf(C4(hv[i][m],kk), w[0], acc[i][m][0]);
                            acc[i][m][1] = fmaf(C4(hv[i][m],kk), w[1], acc[i][m][1]);
                        }
                }
            }
            const float sc = 0.08838834764831845f;   // 1/sqrt(128)
            #pragma unroll
            for (int i = 0; i < 2; ++i) {
                const int r = rg*2 + i;
                const float* xp = xr + r*192;
                float* op = out + (size_t)(row0 + r)*XDIM + 128;
                #pragma unroll
                for (int j = 0; j < 2; ++j) {
                    const int c = cg + 32*j;
                    #pragma unroll
                    for (int m = 0; m < 3; ++m)
                        op[c*3+m] = xp[c*3+m] + acc[i][m][j]*sc;
                }
            }
        }
    } else {
        //===================== l = 2 (32 ch x 5 comps) =====================
        const int row0 = (bid - 2*TILES) * TM;
        float* xr = lds;           // [16][160] raw, layout c*5+m
        float* xn = lds + 2560;    // [5][16][32]
        float* hb = lds + 5120;    // [5][16][64]

        for (int idx = tid; idx < 640; idx += 256) {
            const int r = idx / 40, c4 = idx - r*40;
            *(float4*)(xr + r*160 + c4*4) =
                *(const float4*)(x + (size_t)(row0 + r)*XDIM + 320 + c4*4);
        }
        __syncthreads();

        { // ---- RMS over channel norms (16 thr/row, 2 ch/thr) ----
            const int r = tid >> 4, t = tid & 15;
            const float* xp = xr + r*160 + t*10;     // channels 2t, 2t+1
            float v[10];
            #pragma unroll
            for (int i = 0; i < 10; ++i) v[i] = xp[i];
            float s = 0.f;
            #pragma unroll
            for (int i = 0; i < 10; ++i) s += v[i]*v[i];
            #pragma unroll
            for (int m = 8; m >= 1; m >>= 1) s += __shfl_xor(s, m);
            const float ri = 1.0f / sqrtf(s * (1.0f/32.0f) + 1e-5f);
            const float w0 = nw2[2*t], w1 = nw2[2*t+1];
            #pragma unroll
            for (int m = 0; m < 5; ++m) {
                float2 y = make_float2(v[m]*ri*w0, v[5+m]*ri*w1);
                *(float2*)(xn + m*512 + r*32 + t*2) = y;
            }
        }
        __syncthreads();

        { // ---- pre-linear [32->64] x5 + gate; 2r x 5m x 2c ----
            const int cg = tid & 31;
            const int rg = tid >> 5;
            float acc[2][5][2] = {};
            const float* wp = pw2 + cg;
            for (int k = 0; k < 32; k += 4) {
                float4 xv[2][5];
                #pragma unroll
                for (int i = 0; i < 2; ++i)
                    #pragma unroll
                    for (int m = 0; m < 5; ++m)
                        xv[i][m] = *(const float4*)(xn + m*512 + (rg*2+i)*32 + k);
                #pragma unroll
                for (int kk = 0; kk < 4; ++kk) {
                    const float w[2] = { wp[0], wp[32] };
                    wp += 64;
                    #pragma unroll
                    for (int i = 0; i < 2; ++i)
                        #pragma unroll
                        for (int m = 0; m < 5; ++m) {
                            acc[i][m][0] = fmaf(C4(xv[i][m],kk), w[0], acc[i][m][0]);
                            acc[i][m][1] = fmaf(C4(xv[i][m],kk), w[1], acc[i][m][1]);
                        }
                }
            }
            const float sc = 0.17677669529663687f;   // 1/sqrt(32)
            #pragma unroll
            for (int i = 0; i < 2; ++i) {
                const int r = rg*2 + i;
                #pragma unroll
                for (int j = 0; j < 2; ++j) {
                    const int o = cg + 32*j;
                    float hm[5], s2 = 1e-12f;
                    #pragma unroll
                    for (int m = 0; m < 5; ++m) { hm[m] = acc[i][m][j]*sc; s2 += hm[m]*hm[m]; }
                    const float g = sigm(sqrtf(s2));
                    #pragma unroll
                    for (int m = 0; m < 5; ++m) hb[m*1024 + r*64 + o] = hm[m]*g;
                }
            }
        }
        __syncthreads();

        { // ---- post-linear [64->32] x5 + residual; 2r x 5m x 1c ----
            const int cg = tid & 31;
            const int rg = tid >> 5;
            float acc[2][5] = {};
            const float* wp = qw2 + cg;
            for (int k = 0; k < 64; k += 4) {
                float4 hv[2][5];
                #pragma unroll
                for (int i = 0; i < 2; ++i)
                    #pragma unroll
                    for (int m = 0; m < 5; ++m)
                        hv[i][m] = *(const float4*)(hb + m*1024 + (rg*2+i)*64 + k);
                #pragma unroll
                for (int kk = 0; kk < 4; ++kk) {
                    const float w0 = wp[0];
                    wp += 32;
                    #pragma unroll
                    for (int i = 0; i < 2; ++i)
                        #pragma unroll
                        for (int m = 0; m < 5; ++m)
                            acc[i][m] = fmaf(C4(hv[i][m],kk), w0, acc[i][m]);
                }
            }
            const float sc = 0.125f;                 // 1/sqrt(64)
            #pragma unroll
            for (int i = 0; i < 2; ++i) {
                const int r = rg*2 + i;
                const float* xp = xr + r*160;
                float* op = out + (size_t)(row0 + r)*XDIM + 320;
                #pragma unroll
                for (int m = 0; m < 5; ++m)
                    op[cg*5+m] = xp[cg*5+m] + acc[i][m]*sc;
            }
        }
    }
}

extern "C" void kernel_launch(void* const* d_in, const int* in_sizes, int n_in,
                              void* d_out, int out_size, void* d_ws, size_t ws_size,
                              hipStream_t stream) {
    const float* x   = (const float*)d_in[0];
    const float* nw0 = (const float*)d_in[1];
    const float* nb0 = (const float*)d_in[2];
    const float* nw1 = (const float*)d_in[3];
    const float* nw2 = (const float*)d_in[4];
    const float* pw0 = (const float*)d_in[5];
    const float* pw1 = (const float*)d_in[6];
    const float* pw2 = (const float*)d_in[7];
    const float* qw0 = (const float*)d_in[8];
    const float* qw1 = (const float*)d_in[9];
    const float* qw2 = (const float*)d_in[10];
    float* out = (float*)d_out;

    ff_fused<<<dim3(3 * TILES), dim3(256), 0, stream>>>(
        x, nw0, nb0, nw1, nw2, pw0, pw1, pw2, qw0, qw1, qw2, out);
}